// Round 5
// baseline (167.265 us; speedup 1.0000x reference)
//
#include <hip/hip_runtime.h>
#include <stdint.h>

#define B_ 32
#define P_ 8732
#define PPAD 8736      // P_ rounded up to x4 for uint4 key loads
#define C_ 21
#define TOPK 200
#define CONF_T 0.01f
#define NMS_T 0.45f
#define NCH2 35        // ceil(P_/256)
#define GT 4           // tasks per block
#define TT 256         // threads per task
#define NTB (GT * TT)  // 1024
#define KV4 9          // ceil((PPAD/4)/TT)
#define NTASK (B_ * C_)
#define NBLK (NTASK / GT)   // 168

__device__ __forceinline__ uint32_t f2s(float f) {
    uint32_t u = __float_as_uint(f);
    return (u & 0x80000000u) ? ~u : (u | 0x80000000u);
}
__device__ __forceinline__ float s2f(uint32_t s) {
    uint32_t b = (s & 0x80000000u) ? (s & 0x7FFFFFFFu) : ~s;
    return __uint_as_float(b);
}

// conf (B,P,C) f32 -> (B,C,PPAD) sortable-u32 keys, threshold applied, pads=0
__global__ __launch_bounds__(256) void transpose_keys(const float* __restrict__ conf,
                                                      uint32_t* __restrict__ keys) {
    const int b = blockIdx.x / NCH2;
    const int ch = blockIdx.x % NCH2;
    const int p0 = ch * 256;
    const int n = min(256, P_ - p0);
    const int tid = threadIdx.x;
    __shared__ float tile[256 * C_];
    const float* src = conf + ((size_t)b * P_ + p0) * C_;
    const int tot = n * C_;
    for (int i = tid; i < tot; i += 256) tile[i] = src[i];
    __syncthreads();
    uint32_t* dst = keys + (size_t)b * C_ * PPAD + p0;
    if (tid < n) {
        #pragma unroll
        for (int c = 0; c < C_; ++c) {
            float v = tile[tid * C_ + c];
            v = (v > CONF_T) ? v : -1.0f;
            dst[(size_t)c * PPAD + tid] = f2s(v);
        }
    }
    if (ch == NCH2 - 1 && tid >= n && tid < n + (PPAD - P_)) {
        #pragma unroll
        for (int c = 0; c < C_; ++c) dst[(size_t)c * PPAD + tid] = 0u;
    }
}

template<bool RAW>
__global__ __launch_bounds__(NTB, 4) void detect_kernel(
    const float* __restrict__ loc, const float* __restrict__ prior,
    const uint32_t* __restrict__ keys, const float* __restrict__ conf,
    float* __restrict__ out)
{
    const int tid  = threadIdx.x;
    const int sub  = tid >> 8;         // task slot in block
    const int tt   = tid & 255;        // thread within task
    const int lane = tid & 63;
    const int wv   = (tid >> 6) & 3;   // wave within task
    const int task = blockIdx.x * GT + sub;   // 672 = 168*4 exact
    const int b = task / C_;
    const int c = task % C_;
    float* outp = out + (size_t)task * TOPK * 5;

    __shared__ uint64_t cand[GT][256];
    __shared__ float4 bbox[GT][TOPK];
    __shared__ float bar[GT][TOPK], bs[GT][TOPK];
    __shared__ unsigned long long msk[GT][TOPK * 4];
    __shared__ unsigned long long vmask[GT][4];
    __shared__ int order[GT][TOPK];
    __shared__ int s_cnt[GT], s_nk[GT];
    __shared__ uint64_t warr[GT][4];
    __shared__ uint32_t s_donemask;

    // ---- load this task's keys into registers as uint4 (pads/c==0 -> 0) ----
    uint4 kv[KV4];
    if (!RAW) {
        const uint4* kp = (const uint4*)(keys + (size_t)task * PPAD);
        #pragma unroll
        for (int r = 0; r < KV4; ++r) {
            int q = tt + r * TT;
            kv[r] = (c != 0 && q < PPAD / 4) ? kp[q] : make_uint4(0u, 0u, 0u, 0u);
        }
    } else {
        const float* sp = conf + (size_t)b * P_ * C_ + c;
        #pragma unroll
        for (int r = 0; r < KV4; ++r) {
            uint32_t uu[4];
            #pragma unroll
            for (int q = 0; q < 4; ++q) {
                int p = (tt + r * TT) * 4 + q;
                if (c != 0 && p < P_) {
                    float v = sp[(size_t)p * C_];
                    v = (v > CONF_T) ? v : -1.0f;
                    uu[q] = f2s(v);
                } else uu[q] = 0u;
            }
            kv[r] = make_uint4(uu[0], uu[1], uu[2], uu[3]);
        }
    }

    // ---- exact top-200 threshold via binary search on the key value ----
    // Resolves 2 bits/step via 3 count-probes; exits when count(>=pref) in [200,256].
    if (tid == 0) s_donemask = 0;
    if (tt == 0) s_cnt[sub] = 0;
    __syncthreads();
    if (c == 0 && tt == 0) atomicOr(&s_donemask, 1u << sub);
    __syncthreads();

    uint32_t pref = 0, cprev = KV4 * TT * 4;
    int bp = 30;
    bool done = (c == 0);
    while (s_donemask != 0xFu) {
        if (!done) {
            const uint32_t tA = pref | (1u << bp);
            const uint32_t tB = pref | (2u << bp);
            const uint32_t tC = pref | (3u << bp);
            uint32_t cA = 0, cB = 0, cC = 0;
            #pragma unroll
            for (int r = 0; r < KV4; ++r) {
                const uint32_t uu[4] = {kv[r].x, kv[r].y, kv[r].z, kv[r].w};
                #pragma unroll
                for (int q = 0; q < 4; ++q) {
                    const uint32_t u = uu[q];
                    cA += (u >= tA); cB += (u >= tB); cC += (u >= tC);
                }
            }
            // pack 3 counts (each <= 9216 < 2^21) into one u64, wave-tree-reduce
            unsigned long long pk = (unsigned long long)cA
                                  | ((unsigned long long)cB << 21)
                                  | ((unsigned long long)cC << 42);
            #pragma unroll
            for (int d = 1; d < 64; d <<= 1) pk += __shfl_down(pk, d);
            if (lane == 0) warr[sub][wv] = pk;
        }
        __syncthreads();
        if (!done) {
            const unsigned long long tot = warr[sub][0] + warr[sub][1]
                                         + warr[sub][2] + warr[sub][3];
            const uint32_t M = (1u << 21) - 1;
            const uint32_t cA = (uint32_t)tot & M;
            const uint32_t cB = (uint32_t)(tot >> 21) & M;
            const uint32_t cC = (uint32_t)(tot >> 42) & M;
            uint32_t cNew;
            if      (cC >= TOPK) { pref |= (3u << bp); cNew = cC; }
            else if (cB >= TOPK) { pref |= (2u << bp); cNew = cB; }
            else if (cA >= TOPK) { pref |= (1u << bp); cNew = cA; }
            else                 { cNew = cprev; }
            cprev = cNew;
            bp -= 2;
            if (cNew <= 256 || bp < 0) {
                done = true;
                if (tt == 0) atomicOr(&s_donemask, 1u << sub);
            }
        }
        __syncthreads();
    }
    const uint32_t vthr = pref;

    // ---- compact candidates >= vthr ----
    if (c != 0) {
        #pragma unroll
        for (int r = 0; r < KV4; ++r) {
            const int pb = (tt + r * TT) * 4;
            const uint32_t uu[4] = {kv[r].x, kv[r].y, kv[r].z, kv[r].w};
            #pragma unroll
            for (int q = 0; q < 4; ++q) {
                const uint32_t u = uu[q];
                if (u >= vthr) {
                    int pos = atomicAdd(&s_cnt[sub], 1);
                    if (pos < 256) cand[sub][pos] = ((uint64_t)u << 32)
                                                  | (uint32_t)(~(uint32_t)(pb + q));
                }
            }
        }
    }
    __syncthreads();
    if (tt >= s_cnt[sub]) cand[sub][tt] = 0ull;     // pad sorts to the end
    for (int i2 = tt; i2 < TOPK * 4; i2 += TT) msk[sub][i2] = 0ull;
    __syncthreads();

    // ---- bitonic sort 256 keys desc (val desc, idx asc) == jax.lax.top_k ----
    uint64_t v = cand[sub][tt];
    for (int kk = 2; kk <= 256; kk <<= 1) {
        for (int j = kk >> 1; j > 0; j >>= 1) {
            if (j >= 64) {
                __syncthreads();
                cand[sub][tt] = v;
                __syncthreads();
                uint64_t pv = cand[sub][tt ^ j];
                bool keepmax = (((tt & j) == 0) == ((tt & kk) == 0));
                v = keepmax ? (v > pv ? v : pv) : (v < pv ? v : pv);
            } else {
                uint64_t pv = __shfl_xor(v, j);
                bool keepmax = (((tt & j) == 0) == ((tt & kk) == 0));
                v = keepmax ? (v > pv ? v : pv) : (v < pv ? v : pv);
            }
        }
    }

    // ---- decode top-200 boxes (exact ref f32 op order, no contraction) ----
    float my_sc = -1.0f;
    if (c != 0 && tt < TOPK) {
        uint32_t su = (uint32_t)(v >> 32);
        int p = (int)(~(uint32_t)v);
        my_sc = s2f(su);
        const float4 l4 = *(const float4*)(loc + ((size_t)b * P_ + p) * 4);
        const float4 pr = *(const float4*)(prior + (size_t)p * 4);
        float cx = __fadd_rn(pr.x, __fmul_rn(__fmul_rn(l4.x, 0.1f), pr.z));
        float cy = __fadd_rn(pr.y, __fmul_rn(__fmul_rn(l4.y, 0.1f), pr.w));
        float ew = (float)exp((double)__fmul_rn(l4.z, 0.2f));
        float eh = (float)exp((double)__fmul_rn(l4.w, 0.2f));
        float w  = __fmul_rn(pr.z, ew);
        float h  = __fmul_rn(pr.w, eh);
        float x1 = __fsub_rn(cx, __fmul_rn(w, 0.5f));
        float y1 = __fsub_rn(cy, __fmul_rn(h, 0.5f));
        float x2 = __fadd_rn(x1, w);
        float y2 = __fadd_rn(y1, h);
        bs[sub][tt] = my_sc;
        bbox[sub][tt] = make_float4(x1, y1, x2, y2);
        bar[sub][tt] = __fmul_rn(__fsub_rn(x2, x1), __fsub_rn(y2, y1));
    }
    {
        unsigned long long bm = __ballot(tt < TOPK && my_sc > CONF_T);
        if (lane == 0) vmask[sub][wv] = bm;
    }
    __syncthreads();

    // ---- pairwise IoU: balanced row-pairing (2 sub-lanes), div tie-band screened ----
    if (c != 0 && tt < 2 * (TOPK / 2)) {
        const int rp = tt >> 1;        // row-pair id in [0,100)
        const int s  = tt & 1;
        #pragma unroll
        for (int pass = 0; pass < 2; ++pass) {
            const int j  = pass ? (199 - rp) : rp;
            const int i0 = j + 1 + s;
            const float4 bj = bbox[sub][j];
            const float  aj = bar[sub][j];
            for (int i = i0; i < TOPK; i += 2) {
                const float4 bi = bbox[sub][i];
                float xx1 = fmaxf(bj.x, bi.x);
                float yy1 = fmaxf(bj.y, bi.y);
                float xx2 = fminf(bj.z, bi.z);
                float yy2 = fminf(bj.w, bi.w);
                float dx = fmaxf(__fsub_rn(xx2, xx1), 0.0f);
                float dy = fmaxf(__fsub_rn(yy2, yy1), 0.0f);
                float inter = __fmul_rn(dx, dy);
                if (inter > 0.0f) {
                    float uni = __fsub_rn(__fadd_rn(aj, bar[sub][i]), inter);
                    float t45 = __fmul_rn(NMS_T, uni);
                    float mar = __fmul_rn(t45, 1e-6f);
                    bool sup;
                    if (inter > __fadd_rn(t45, mar)) sup = true;
                    else if (inter < __fsub_rn(t45, mar)) sup = false;
                    else sup = (inter / uni > NMS_T);   // exact IEEE path, tie band only
                    if (sup) atomicOr(&msk[sub][j * 4 + (i >> 6)], 1ull << (i & 63));
                }
            }
        }
    }
    __syncthreads();

    // ---- greedy NMS: per-task wave-parallel bitmask scan, rows in lane registers ----
    if (tt < 64) {
        const int L = tt;
        unsigned long long s0 = 0, s1 = 0, s2 = 0, s3 = 0;
        const unsigned long long vm0 = vmask[sub][0], vm1 = vmask[sub][1],
                                 vm2 = vmask[sub][2], vm3 = vmask[sub][3];
        int nk = 0;
        #pragma unroll
        for (int w = 0; w < 4; ++w) {
            const int j = (w << 6) | L;
            unsigned long long r0 = 0, r1 = 0, r2 = 0, r3 = 0;
            if (j < TOPK) {
                const unsigned long long* mr = &msk[sub][j * 4];
                r0 = mr[0]; r1 = mr[1]; r2 = mr[2]; r3 = mr[3];
            }
            const unsigned long long vw = (w == 0) ? vm0 : (w == 1) ? vm1
                                        : (w == 2) ? vm2 : vm3;
            const unsigned long long sw = (w == 0) ? s0 : (w == 1) ? s1
                                        : (w == 2) ? s2 : s3;
            unsigned long long alive = vw & ~sw;
            while (alive) {
                int jl = __ffsll(alive) - 1;
                if (L == 0) order[sub][nk] = (w << 6) | jl;
                ++nk;
                s0 |= __shfl(r0, jl); s1 |= __shfl(r1, jl);
                s2 |= __shfl(r2, jl); s3 |= __shfl(r3, jl);
                const unsigned long long swn = (w == 0) ? s0 : (w == 1) ? s1
                                             : (w == 2) ? s2 : s3;
                alive &= ~swn;
                alive &= ~(1ull << jl);
            }
        }
        if (L == 0) s_nk[sub] = nk;
    }
    __syncthreads();

    // ---- compacted output (c==0: nk=0 -> zeros) ----
    const int nk = (c != 0) ? s_nk[sub] : 0;
    for (int e = tt; e < TOPK * 5; e += TT) {
        int r = e / 5;
        int f = e - r * 5;
        float val = 0.0f;
        if (r < nk) {
            int j = order[sub][r];
            float4 bb = bbox[sub][j];
            val = (f == 0) ? bs[sub][j] : (f == 1) ? bb.x : (f == 2) ? bb.y
                : (f == 3) ? bb.z : bb.w;
        }
        outp[e] = val;
    }
}

extern "C" void kernel_launch(void* const* d_in, const int* in_sizes, int n_in,
                              void* d_out, int out_size, void* d_ws, size_t ws_size,
                              hipStream_t stream) {
    const float* loc   = (const float*)d_in[0];
    const float* conf  = (const float*)d_in[1];
    const float* prior = (const float*)d_in[2];
    float* out = (float*)d_out;

    const size_t need = (size_t)B_ * C_ * PPAD * sizeof(uint32_t);
    if (ws_size >= need) {
        uint32_t* keys = (uint32_t*)d_ws;
        transpose_keys<<<B_ * NCH2, 256, 0, stream>>>(conf, keys);
        detect_kernel<false><<<NBLK, NTB, 0, stream>>>(loc, prior, keys, conf, out);
    } else {
        detect_kernel<true><<<NBLK, NTB, 0, stream>>>(loc, prior, nullptr, conf, out);
    }
}

// Round 6
// 136.302 us; speedup vs baseline: 1.2272x; 1.2272x over previous
//
#include <hip/hip_runtime.h>
#include <stdint.h>

#define B_ 32
#define P_ 8732
#define PPAD 8736      // P_ rounded up to x4 for uint4 key loads
#define C_ 21
#define TOPK 200
#define CONF_T 0.01f
#define NMS_T 0.45f
#define NCH2 35        // ceil(P_/256)
#define NT 512
#define KV4 5          // ceil((PPAD/4)/NT)

__device__ __forceinline__ uint32_t f2s(float f) {
    uint32_t u = __float_as_uint(f);
    return (u & 0x80000000u) ? ~u : (u | 0x80000000u);
}
__device__ __forceinline__ float s2f(uint32_t s) {
    uint32_t b = (s & 0x80000000u) ? (s & 0x7FFFFFFFu) : ~s;
    return __uint_as_float(b);
}

// conf (B,P,C) f32 -> (B,C,PPAD) sortable-u32 keys, threshold applied, pads=0
__global__ __launch_bounds__(256) void transpose_keys(const float* __restrict__ conf,
                                                      uint32_t* __restrict__ keys) {
    const int b = blockIdx.x / NCH2;
    const int ch = blockIdx.x % NCH2;
    const int p0 = ch * 256;
    const int n = min(256, P_ - p0);
    const int tid = threadIdx.x;
    __shared__ float tile[256 * C_];
    const float* src = conf + ((size_t)b * P_ + p0) * C_;
    const int tot = n * C_;
    for (int i = tid; i < tot; i += 256) tile[i] = src[i];
    __syncthreads();
    uint32_t* dst = keys + (size_t)b * C_ * PPAD + p0;
    if (tid < n) {
        #pragma unroll
        for (int c = 0; c < C_; ++c) {
            float v = tile[tid * C_ + c];
            v = (v > CONF_T) ? v : -1.0f;
            dst[(size_t)c * PPAD + tid] = f2s(v);
        }
    }
    if (ch == NCH2 - 1 && tid >= n && tid < n + (PPAD - P_)) {
        #pragma unroll
        for (int c = 0; c < C_; ++c) dst[(size_t)c * PPAD + tid] = 0u;
    }
}

template<bool RAW>
__global__ __launch_bounds__(NT, 6) void detect_kernel(
    const float* __restrict__ loc, const float* __restrict__ prior,
    const uint32_t* __restrict__ keys, const float* __restrict__ conf,
    float* __restrict__ out)
{
    const int task = blockIdx.x;
    const int b = task / C_;
    const int c = task % C_;
    const int tid = threadIdx.x;
    const int lane = tid & 63;
    float* outp = out + (size_t)task * TOPK * 5;

    if (c == 0) {  // out.at[:,0].set(0.0)
        for (int e = tid; e < TOPK * 5; e += NT) outp[e] = 0.0f;
        return;
    }

    __shared__ uint32_t hist[512];            // two ping-pong 256-bin buffers
    __shared__ uint64_t cand[256];
    __shared__ float4 bbox[TOPK];
    __shared__ float bar[TOPK], bs[TOPK];
    __shared__ unsigned long long msk[TOPK * 4];
    __shared__ unsigned long long vmask[4];
    __shared__ int order[TOPK];
    __shared__ int s_cnt, s_nk, s_flags;
    __shared__ uint32_t s_pref, s_want;

    // ---- load this task's 8736 keys into registers as uint4 (pads = 0) ----
    uint4 kv[KV4];
    if (!RAW) {
        const uint4* kp = (const uint4*)(keys + (size_t)task * PPAD);
        #pragma unroll
        for (int r = 0; r < KV4; ++r) {
            int q = tid + r * NT;
            kv[r] = (q < PPAD / 4) ? kp[q] : make_uint4(0u, 0u, 0u, 0u);
        }
    } else {
        const float* sp = conf + (size_t)b * P_ * C_ + c;
        #pragma unroll
        for (int r = 0; r < KV4; ++r) {
            uint32_t uu[4];
            #pragma unroll
            for (int c4 = 0; c4 < 4; ++c4) {
                int p = (tid + r * NT) * 4 + c4;
                if (p < P_) {
                    float v = sp[(size_t)p * C_];
                    v = (v > CONF_T) ? v : -1.0f;
                    uu[c4] = f2s(v);
                } else uu[c4] = 0u;
            }
            kv[r] = make_uint4(uu[0], uu[1], uu[2], uu[3]);
        }
    }

    // ---- one-time zeroing (hidden under the in-flight global key loads) ----
    if (tid == 0) s_cnt = 0;
    if (tid < 512) hist[tid] = 0;
    for (int i2 = tid; i2 < TOPK * 4; i2 += NT) msk[i2] = 0ull;
    __syncthreads();

    // ---- radix-select with early exit; 2 barriers per level ----
    uint32_t pref = 0, want = TOPK;
    for (int level = 3; level >= 0; --level) {
        const int shift = level * 8;
        uint32_t* H = hist + ((((3 - level) & 1)) << 8);   // ping-pong buffer
        if (level <= 1) {                                   // rare path: re-zero
            if (tid < 256) H[tid] = 0;
            __syncthreads();
        }
        if (level == 3) {
            // ballot-aggregated histogram (scores cluster into few top-byte bins)
            auto agg = [&](uint32_t u) {
                uint32_t bin = u >> 24;
                unsigned long long rem = __ballot(1);
                while (rem) {
                    int src = __ffsll(rem) - 1;
                    uint32_t bref = __shfl(bin, src);
                    unsigned long long same = __ballot(bin == bref) & rem;
                    if (lane == src) atomicAdd(&H[bref], (uint32_t)__popcll(same));
                    rem &= ~same;
                }
            };
            #pragma unroll
            for (int r = 0; r < KV4; ++r) {
                agg(kv[r].x); agg(kv[r].y); agg(kv[r].z); agg(kv[r].w);
            }
        } else {
            const uint32_t himask = 0xFFFFFFFFu << (shift + 8);
            auto one = [&](uint32_t u) {
                if ((u & himask) == pref) atomicAdd(&H[(u >> shift) & 0xFFu], 1u);
            };
            #pragma unroll
            for (int r = 0; r < KV4; ++r) {
                one(kv[r].x); one(kv[r].y); one(kv[r].z); one(kv[r].w);
            }
        }
        __syncthreads();
        // wave 0 computes the crossing bin: 4 bins/lane + shfl suffix-scan
        if (tid < 64) {
            uint4 bb = ((const uint4*)H)[tid];
            uint32_t s = bb.x + bb.y + bb.z + bb.w;
            uint32_t I = s;
            #pragma unroll
            for (int d = 1; d < 64; d <<= 1) {
                uint32_t t2 = __shfl_down(I, d);
                if (lane + d < 64) I += t2;
            }
            const uint32_t above = I - s;       // keys in bins above this lane's 4
            const uint32_t e3 = above,      i3 = above + bb.w;
            const uint32_t e2 = i3,         i2 = i3 + bb.z;
            const uint32_t e1 = i2,         i1 = i2 + bb.y;
            const uint32_t e0 = i1,         i0 = i1 + bb.x;
            const uint32_t base = (uint32_t)TOPK - want;   // qualified above this level
            if (i3 >= want && e3 < want) {
                s_pref = pref | ((uint32_t)(4 * tid + 3) << shift);
                s_want = want - e3; s_flags = (base + i3 <= 256);
            }
            if (i2 >= want && e2 < want) {
                s_pref = pref | ((uint32_t)(4 * tid + 2) << shift);
                s_want = want - e2; s_flags = (base + i2 <= 256);
            }
            if (i1 >= want && e1 < want) {
                s_pref = pref | ((uint32_t)(4 * tid + 1) << shift);
                s_want = want - e1; s_flags = (base + i1 <= 256);
            }
            if (i0 >= want && e0 < want) {
                s_pref = pref | ((uint32_t)(4 * tid + 0) << shift);
                s_want = want - e0; s_flags = (base + i0 <= 256);
            }
        }
        __syncthreads();
        pref = s_pref; want = s_want;
        if (s_flags) break;                     // uniform; written exactly once per level
    }
    const uint32_t vthr = pref;   // prefix threshold; full sort below restores exactness

    // ---- compact candidates >= vthr ----
    #pragma unroll
    for (int r = 0; r < KV4; ++r) {
        const int pb = (tid + r * NT) * 4;
        uint32_t uu[4] = {kv[r].x, kv[r].y, kv[r].z, kv[r].w};
        #pragma unroll
        for (int c4 = 0; c4 < 4; ++c4) {
            uint32_t u = uu[c4];
            if (u >= vthr) {
                int pos = atomicAdd(&s_cnt, 1);
                if (pos < 256) cand[pos] = ((uint64_t)u << 32) | (uint32_t)(~(uint32_t)(pb + c4));
            }
        }
    }
    __syncthreads();
    if (tid < 256 && tid >= s_cnt) cand[tid] = 0ull;   // pad sorts to the end
    __syncthreads();

    // ---- bitonic sort 256 keys desc (val desc, idx asc) == jax.lax.top_k ----
    uint64_t v = (tid < 256) ? cand[tid] : 0ull;
    for (int kk = 2; kk <= 256; kk <<= 1) {
        for (int j = kk >> 1; j > 0; j >>= 1) {
            if (j >= 64) {
                __syncthreads();
                if (tid < 256) cand[tid] = v;
                __syncthreads();
                if (tid < 256) {
                    uint64_t pv = cand[tid ^ j];
                    bool keepmax = (((tid & j) == 0) == ((tid & kk) == 0));
                    v = keepmax ? (v > pv ? v : pv) : (v < pv ? v : pv);
                }
            } else if (tid < 256) {
                uint64_t pv = __shfl_xor(v, j);
                bool keepmax = (((tid & j) == 0) == ((tid & kk) == 0));
                v = keepmax ? (v > pv ? v : pv) : (v < pv ? v : pv);
            }
        }
    }

    // ---- decode top-200 boxes (exact ref f32 op order, no contraction) ----
    float my_sc = -1.0f;
    if (tid < TOPK) {
        uint32_t su = (uint32_t)(v >> 32);
        int p = (int)(~(uint32_t)v);
        my_sc = s2f(su);
        const float4 l4 = *(const float4*)(loc + ((size_t)b * P_ + p) * 4);
        const float4 pr = *(const float4*)(prior + (size_t)p * 4);
        float cx = __fadd_rn(pr.x, __fmul_rn(__fmul_rn(l4.x, 0.1f), pr.z));
        float cy = __fadd_rn(pr.y, __fmul_rn(__fmul_rn(l4.y, 0.1f), pr.w));
        float ew = (float)exp((double)__fmul_rn(l4.z, 0.2f));
        float eh = (float)exp((double)__fmul_rn(l4.w, 0.2f));
        float w  = __fmul_rn(pr.z, ew);
        float h  = __fmul_rn(pr.w, eh);
        float x1 = __fsub_rn(cx, __fmul_rn(w, 0.5f));
        float y1 = __fsub_rn(cy, __fmul_rn(h, 0.5f));
        float x2 = __fadd_rn(x1, w);
        float y2 = __fadd_rn(y1, h);
        bs[tid] = my_sc;
        bbox[tid] = make_float4(x1, y1, x2, y2);
        bar[tid] = __fmul_rn(__fsub_rn(x2, x1), __fsub_rn(y2, y1));
    }
    {
        unsigned long long bm = __ballot(tid < TOPK && my_sc > CONF_T);
        if (lane == 0 && tid < 256) vmask[tid >> 6] = bm;
    }
    __syncthreads();

    // ---- pairwise IoU: balanced row-pairing, div screened to a tie band ----
    if (tid < 500) {
        const int rp = tid / 5;        // row-pair id in [0,100)
        const int s  = tid - rp * 5;   // sub-lane in [0,5)
        #pragma unroll
        for (int pass = 0; pass < 2; ++pass) {
            const int j  = pass ? (199 - rp) : rp;
            const int i0 = pass ? (200 - rp + s) : (rp + 1 + s);
            const float4 bj = bbox[j];
            const float  aj = bar[j];
            for (int i = i0; i < TOPK; i += 5) {
                const float4 bi = bbox[i];
                float xx1 = fmaxf(bj.x, bi.x);
                float yy1 = fmaxf(bj.y, bi.y);
                float xx2 = fminf(bj.z, bi.z);
                float yy2 = fminf(bj.w, bi.w);
                float dx = fmaxf(__fsub_rn(xx2, xx1), 0.0f);
                float dy = fmaxf(__fsub_rn(yy2, yy1), 0.0f);
                float inter = __fmul_rn(dx, dy);
                if (inter > 0.0f) {
                    float uni = __fsub_rn(__fadd_rn(aj, bar[i]), inter);
                    float t45 = __fmul_rn(NMS_T, uni);
                    float mar = __fmul_rn(t45, 1e-6f);
                    bool sup;
                    if (inter > __fadd_rn(t45, mar)) sup = true;
                    else if (inter < __fsub_rn(t45, mar)) sup = false;
                    else sup = (inter / uni > NMS_T);   // exact IEEE path, tie band only
                    if (sup) atomicOr(&msk[j * 4 + (i >> 6)], 1ull << (i & 63));
                }
            }
        }
    }
    __syncthreads();

    // ---- greedy NMS: word-blocked wave-0 scan (1 shfl/pick, deferred cross-word OR) ----
    if (tid < 64) {
        const int L = tid;
        auto or_reduce = [&](unsigned long long x) {
            #pragma unroll
            for (int d = 1; d < 64; d <<= 1) x |= __shfl_xor(x, d);
            return x;
        };
        unsigned long long s1 = 0, s2 = 0, s3 = 0;   // incoming suppression, words 1..3
        int nk = 0;
        #pragma unroll
        for (int w = 0; w < 4; ++w) {
            const int j = (w << 6) | L;
            unsigned long long r0 = 0, r1 = 0, r2 = 0, r3 = 0;
            if (j < TOPK) {
                const unsigned long long* mr = &msk[j * 4];
                r0 = mr[0]; r1 = mr[1]; r2 = mr[2]; r3 = mr[3];
            }
            const unsigned long long rself = (w == 0) ? r0 : (w == 1) ? r1
                                           : (w == 2) ? r2 : r3;
            unsigned long long sw = (w == 0) ? 0ull : (w == 1) ? s1
                                  : (w == 2) ? s2 : s3;
            unsigned long long alive = vmask[w] & ~sw;
            unsigned long long pm = 0;
            while (alive) {
                int jl = __ffsll(alive) - 1;
                if (L == 0) order[nk] = (w << 6) | jl;
                ++nk;
                sw |= __shfl(rself, jl);             // suppression within this word
                pm |= (1ull << jl);
                alive &= ~(sw | (1ull << jl));
            }
            if (pm) {   // deferred: OR picked rows' later-word masks (mask bits are i>j only)
                const bool picked = (pm >> L) & 1ull;
                if (w == 0) {
                    s1 |= or_reduce(picked ? r1 : 0ull);
                    s2 |= or_reduce(picked ? r2 : 0ull);
                    s3 |= or_reduce(picked ? r3 : 0ull);
                } else if (w == 1) {
                    s2 |= or_reduce(picked ? r2 : 0ull);
                    s3 |= or_reduce(picked ? r3 : 0ull);
                } else if (w == 2) {
                    s3 |= or_reduce(picked ? r3 : 0ull);
                }
            }
        }
        if (L == 0) s_nk = nk;
    }
    __syncthreads();

    // ---- compacted output ----
    const int nk = s_nk;
    for (int e = tid; e < TOPK * 5; e += NT) {
        int r = e / 5;
        int f = e - r * 5;
        float val = 0.0f;
        if (r < nk) {
            int j = order[r];
            float4 bb = bbox[j];
            val = (f == 0) ? bs[j] : (f == 1) ? bb.x : (f == 2) ? bb.y
                : (f == 3) ? bb.z : bb.w;
        }
        outp[e] = val;
    }
}

extern "C" void kernel_launch(void* const* d_in, const int* in_sizes, int n_in,
                              void* d_out, int out_size, void* d_ws, size_t ws_size,
                              hipStream_t stream) {
    const float* loc   = (const float*)d_in[0];
    const float* conf  = (const float*)d_in[1];
    const float* prior = (const float*)d_in[2];
    float* out = (float*)d_out;

    const size_t need = (size_t)B_ * C_ * PPAD * sizeof(uint32_t);
    if (ws_size >= need) {
        uint32_t* keys = (uint32_t*)d_ws;
        transpose_keys<<<B_ * NCH2, 256, 0, stream>>>(conf, keys);
        detect_kernel<false><<<B_ * C_, NT, 0, stream>>>(loc, prior, keys, conf, out);
    } else {
        detect_kernel<true><<<B_ * C_, NT, 0, stream>>>(loc, prior, nullptr, conf, out);
    }
}